// Round 1
// baseline (778.743 us; speedup 1.0000x reference)
//
#include <hip/hip_runtime.h>

#define H_ 4
#define N_ 1024
#define E_ 4096
#define LE_ 16384
#define FN_ 128
#define FE_ 64
#define HT_ 65536   // hash table slots (4x oversized vs 16384 entries)

// ---------------------------------------------------------------------------
// Generic small linear: C[r,o] = b[o] + sum_k X[r,k]*W[o,k]  (naive, for O=4)
// ---------------------------------------------------------------------------
__global__ void lin_naive(const float* __restrict__ X, const float* __restrict__ W,
                          const float* __restrict__ b, float* __restrict__ C,
                          int R, int K, int O) {
  int idx = blockIdx.x * blockDim.x + threadIdx.x;
  if (idx >= R * O) return;
  int r = idx / O, o = idx - r * O;
  float acc = b[o];
  for (int k = 0; k < K; ++k) acc += X[r * K + k] * W[o * K + k];
  C[idx] = acc;
}

// ---------------------------------------------------------------------------
// LDS-tiled linear. W tile staged transposed with an additive bank swizzle:
// element (ol,k) lives at Wt[k*OTILE + ((ol+k)&(OTILE-1))] -> both the staging
// write (lanes sweep k) and the dot-loop read (lanes sweep ol=tid) hit
// consecutive banks. Block = OTILE threads; each block does RPB rows.
// ---------------------------------------------------------------------------
template<int K, int OTILE, int RPB, bool RELU>
__global__ void lin_tiled(const float* __restrict__ X, const float* __restrict__ W,
                          const float* __restrict__ b, float* __restrict__ C,
                          int R, int O) {
  __shared__ float Wt[K * OTILE];
  __shared__ float xs[K];
  const int tid = threadIdx.x;
  const int o0 = blockIdx.y * OTILE;
  const int r0 = blockIdx.x * RPB;
  for (int j = tid; j < K * OTILE; j += OTILE) {
    int ol = j / K, k = j - ol * K;
    Wt[k * OTILE + ((ol + k) & (OTILE - 1))] = W[(o0 + ol) * K + k];
  }
  float bias = b[o0 + tid];
  __syncthreads();
  for (int r = r0; r < r0 + RPB; ++r) {
    for (int k = tid; k < K; k += OTILE) xs[k] = X[r * K + k];
    __syncthreads();
    float acc = bias;
#pragma unroll
    for (int k = 0; k < K; ++k)
      acc += xs[k] * Wt[k * OTILE + ((tid + k) & (OTILE - 1))];
    C[r * O + o0 + tid] = RELU ? fmaxf(acc, 0.f) : acc;
    __syncthreads();
  }
}

// ---------------------------------------------------------------------------
// Node attention: per head h, t[f]=sum_i q[i,f]*k[i]; s[i]=sum_f q[i,f]*t[f];
// sa = softmax_i(s). One block per head, 1024 threads (= N).
// ---------------------------------------------------------------------------
__global__ __launch_bounds__(1024) void node_attn(const float* __restrict__ NQ,
                                                  const float* __restrict__ NK,
                                                  float* __restrict__ sa) {
  const int h = blockIdx.x;
  const int tid = threadIdx.x;
  __shared__ float red[1024];
  __shared__ float t[FN_];
  const float* q = NQ + h * (N_ * FN_);
  const float* kk = NK + h * N_;
  {
    int f = tid & (FN_ - 1), c = tid >> 7;      // 8 chunks of 128 rows
    float p = 0.f;
    for (int i = c * 128; i < c * 128 + 128; ++i) p += q[i * FN_ + f] * kk[i];
    red[tid] = p;
  }
  __syncthreads();
  if (tid < FN_) {
    float s = 0.f;
    for (int c = 0; c < 8; ++c) s += red[c * FN_ + tid];
    t[tid] = s;
  }
  __syncthreads();
  float s = 0.f;
  for (int f = 0; f < FN_; ++f) s += q[tid * FN_ + f] * t[f];
  red[tid] = s;
  __syncthreads();
  for (int off = 512; off > 0; off >>= 1) {
    if (tid < off) red[tid] = fmaxf(red[tid], red[tid + off]);
    __syncthreads();
  }
  float m = red[0];
  __syncthreads();
  float e = expf(s - m);
  red[tid] = e;
  __syncthreads();
  for (int off = 512; off > 0; off >>= 1) {
    if (tid < off) red[tid] += red[tid + off];
    __syncthreads();
  }
  sa[h * N_ + tid] = e / red[0];
}

// ---------------------------------------------------------------------------
// Edge attention: same, E=4096 / FE=64; each thread handles 4 edges.
// ---------------------------------------------------------------------------
__global__ __launch_bounds__(1024) void edge_attn(const float* __restrict__ EQ,
                                                  const float* __restrict__ EK,
                                                  float* __restrict__ sa) {
  const int h = blockIdx.x;
  const int tid = threadIdx.x;
  __shared__ float red[1024];
  __shared__ float t[FE_];
  const float* q = EQ + h * (E_ * FE_);
  const float* kk = EK + h * E_;
  {
    int f = tid & (FE_ - 1), c = tid >> 6;      // 16 chunks of 256 rows
    float p = 0.f;
    for (int j = c * 256; j < c * 256 + 256; ++j) p += q[j * FE_ + f] * kk[j];
    red[tid] = p;
  }
  __syncthreads();
  if (tid < FE_) {
    float s = 0.f;
    for (int c = 0; c < 16; ++c) s += red[c * FE_ + tid];
    t[tid] = s;
  }
  __syncthreads();
  float s[4];
  float lm = -INFINITY;
#pragma unroll
  for (int u = 0; u < 4; ++u) {
    int j = tid * 4 + u;
    float acc = 0.f;
    for (int f = 0; f < FE_; ++f) acc += q[j * FE_ + f] * t[f];
    s[u] = acc;
    lm = fmaxf(lm, acc);
  }
  red[tid] = lm;
  __syncthreads();
  for (int off = 512; off > 0; off >>= 1) {
    if (tid < off) red[tid] = fmaxf(red[tid], red[tid + off]);
    __syncthreads();
  }
  float m = red[0];
  __syncthreads();
  float ev[4], le = 0.f;
#pragma unroll
  for (int u = 0; u < 4; ++u) { ev[u] = expf(s[u] - m); le += ev[u]; }
  red[tid] = le;
  __syncthreads();
  for (int off = 512; off > 0; off >>= 1) {
    if (tid < off) red[tid] += red[tid + off];
    __syncthreads();
  }
  float inv = 1.f / red[0];
#pragma unroll
  for (int u = 0; u < 4; ++u) sa[h * E_ + tid * 4 + u] = ev[u] * inv;
}

// ---------------------------------------------------------------------------
// Duplicate resolution: numpy fancy-assignment semantics = last index wins.
// Node side: dense N*N winner map (atomicMax of edge index, init -1).
// ---------------------------------------------------------------------------
__global__ void node_winner(const int* __restrict__ src, const int* __restrict__ dst,
                            int* __restrict__ Wn) {
  int e = blockIdx.x * blockDim.x + threadIdx.x;
  if (e >= E_) return;
  atomicMax(&Wn[src[e] * N_ + dst[e]], e);
}

// Edge side: open-addressing hash (key = lg_src*E + lg_dst), CAS-claim slot,
// atomicMax the line-edge index. Table init = -1.
__global__ void hash_insert(const int* __restrict__ lgs, const int* __restrict__ lgd,
                            int* __restrict__ hkey, int* __restrict__ hval) {
  int l = blockIdx.x * blockDim.x + threadIdx.x;
  if (l >= LE_) return;
  int key = lgs[l] * E_ + lgd[l];
  unsigned slot = ((unsigned)key * 2654435761u) >> 16;
  slot &= (HT_ - 1);
  while (true) {
    int prev = atomicCAS(&hkey[slot], -1, key);
    if (prev == -1 || prev == key) break;
    slot = (slot + 1) & (HT_ - 1);
  }
  atomicMax(&hval[slot], l);
}

// ---------------------------------------------------------------------------
// node_agg[h, src[e], f] += edge_sa[h,e] * nv[h, dst[e], f]   (winning e only)
// thread = (e, f) pair, loops h.
// ---------------------------------------------------------------------------
__global__ void node_scatter(const int* __restrict__ src, const int* __restrict__ dst,
                             const int* __restrict__ Wn, const float* __restrict__ esa,
                             const float* __restrict__ NV, float* __restrict__ agg) {
  int idx = blockIdx.x * blockDim.x + threadIdx.x;   // E*FN threads
  int e = idx >> 7, f = idx & (FN_ - 1);
  int s = src[e], d = dst[e];
  if (Wn[s * N_ + d] != e) return;
#pragma unroll
  for (int h = 0; h < H_; ++h)
    atomicAdd(&agg[h * (N_ * FN_) + s * FN_ + f],
              esa[h * E_ + e] * NV[h * (N_ * FN_) + d * FN_ + f]);
}

// ---------------------------------------------------------------------------
// edge_agg[h, j, f] += node_sa[h, dst[j]] * ev[h, lg_dst[l], f], j=lg_src[l]
// ---------------------------------------------------------------------------
__global__ void edge_scatter(const int* __restrict__ lgs, const int* __restrict__ lgd,
                             const int* __restrict__ dst, const int* __restrict__ hkey,
                             const int* __restrict__ hval, const float* __restrict__ nsa,
                             const float* __restrict__ EV, float* __restrict__ agg) {
  int idx = blockIdx.x * blockDim.x + threadIdx.x;   // LE*FE threads
  int l = idx >> 6, f = idx & (FE_ - 1);
  int j = lgs[l], c = lgd[l];
  int key = j * E_ + c;
  unsigned slot = ((unsigned)key * 2654435761u) >> 16;
  slot &= (HT_ - 1);
  while (hkey[slot] != key) slot = (slot + 1) & (HT_ - 1);
  if (hval[slot] != l) return;
  int cn = dst[j];
#pragma unroll
  for (int h = 0; h < H_; ++h)
    atomicAdd(&agg[h * (E_ * FE_) + j * FE_ + f],
              nsa[h * N_ + cn] * EV[h * (E_ * FE_) + c * FE_ + f]);
}

// ---------------------------------------------------------------------------
extern "C" void kernel_launch(void* const* d_in, const int* in_sizes, int n_in,
                              void* d_out, int out_size, void* d_ws, size_t ws_size,
                              hipStream_t stream) {
  const float* node_inputs = (const float*)d_in[0];
  const float* edge_inputs = (const float*)d_in[1];
  const int*   src    = (const int*)d_in[2];
  const int*   dst    = (const int*)d_in[3];
  const int*   lg_src = (const int*)d_in[4];
  const int*   lg_dst = (const int*)d_in[5];
  const float* nqW = (const float*)d_in[6];
  const float* nqb = (const float*)d_in[7];
  const float* nkW = (const float*)d_in[8];
  const float* nkb = (const float*)d_in[9];
  const float* nvW = (const float*)d_in[10];
  const float* nvb = (const float*)d_in[11];
  const float* eqW = (const float*)d_in[12];
  const float* eqb = (const float*)d_in[13];
  const float* ekW = (const float*)d_in[14];
  const float* ekb = (const float*)d_in[15];
  const float* evW = (const float*)d_in[16];
  const float* evb = (const float*)d_in[17];
  const float* ncW = (const float*)d_in[18];
  const float* ncb = (const float*)d_in[19];
  const float* ecW = (const float*)d_in[20];
  const float* ecb = (const float*)d_in[21];
  float* out = (float*)d_out;

  // workspace carve-up (floats)
  float* f  = (float*)d_ws;
  float* NQ   = f; f += N_ * H_ * FN_;   // 524288
  float* NV   = f; f += N_ * H_ * FN_;   // 524288
  float* NK   = f; f += N_ * H_;         // 4096
  float* EQ   = f; f += E_ * H_ * FE_;   // 1048576
  float* EV   = f; f += E_ * H_ * FE_;   // 1048576
  float* EK   = f; f += E_ * H_;         // 16384
  float* nsa  = f; f += H_ * N_;         // 4096
  float* esa  = f; f += H_ * E_;         // 16384
  float* nagg = f; f += H_ * N_ * FN_;   // 524288
  float* eagg = f; f += H_ * E_ * FE_;   // 1048576
  int*   Wn   = (int*)f; f += N_ * N_;   // 1048576 ints
  int*   hkey = (int*)f; f += HT_;
  int*   hval = (int*)f; f += HT_;

  // init: winner maps to -1, accumulators to 0 (ws is poisoned every call)
  hipMemsetAsync(nagg, 0, (size_t)H_ * N_ * FN_ * 4, stream);
  hipMemsetAsync(eagg, 0, (size_t)H_ * E_ * FE_ * 4, stream);
  hipMemsetAsync(Wn, 0xFF, (size_t)N_ * N_ * 4, stream);
  hipMemsetAsync(hkey, 0xFF, (size_t)2 * HT_ * 4, stream);  // hkey + hval contiguous

  // projections (flat [rows, H*F] buffers == reshaped [H,rows,F] views)
  lin_tiled<128, 64, 16, false><<<dim3(64, 8), 64, 0, stream>>>(node_inputs, nqW, nqb, NQ, N_, H_ * FN_);
  lin_tiled<128, 64, 16, false><<<dim3(64, 8), 64, 0, stream>>>(node_inputs, nvW, nvb, NV, N_, H_ * FN_);
  lin_naive<<<16, 256, 0, stream>>>(node_inputs, nkW, nkb, NK, N_, FN_, H_);
  lin_tiled<64, 128, 16, false><<<dim3(256, 2), 128, 0, stream>>>(edge_inputs, eqW, eqb, EQ, E_, H_ * FE_);
  lin_tiled<64, 128, 16, false><<<dim3(256, 2), 128, 0, stream>>>(edge_inputs, evW, evb, EV, E_, H_ * FE_);
  lin_naive<<<64, 256, 0, stream>>>(edge_inputs, ekW, ekb, EK, E_, FE_, H_);

  // self-attention softmax scores
  node_attn<<<H_, 1024, 0, stream>>>(NQ, NK, nsa);
  edge_attn<<<H_, 1024, 0, stream>>>(EQ, EK, esa);

  // duplicate-index winners (numpy last-wins == max index)
  node_winner<<<E_ / 256, 256, 0, stream>>>(src, dst, Wn);
  hash_insert<<<LE_ / 256, 256, 0, stream>>>(lg_src, lg_dst, hkey, hval);

  // sparse (proj * A) @ V aggregation
  node_scatter<<<(E_ * FN_) / 256, 256, 0, stream>>>(src, dst, Wn, esa, NV, nagg);
  edge_scatter<<<(LE_ * FE_) / 256, 256, 0, stream>>>(lg_src, lg_dst, dst, hkey, hval, nsa, EV, eagg);

  // output linears + ReLU, straight into d_out
  lin_tiled<128, 64, 16, true><<<dim3(256, 2), 64, 0, stream>>>(nagg, ncW, ncb, out, H_ * N_, FN_);
  lin_tiled<64, 64, 32, true><<<dim3(512, 1), 64, 0, stream>>>(eagg, ecW, ecb, out + H_ * N_ * FN_, H_ * E_, FE_);
}

// Round 2
// 267.551 us; speedup vs baseline: 2.9106x; 2.9106x over previous
//
#include <hip/hip_runtime.h>

#define H_ 4
#define N_ 1024
#define E_ 4096
#define LE_ 16384
#define FN_ 128
#define FE_ 64
#define HT_ 65536   // hash table slots (4x oversized vs LE entries)

// ---------------------------------------------------------------------------
// Register-tiled GEMM: C = [relu](X @ W^T + b). X:[R,K], W:[O,K], C:[R,O].
// BM=BN=64, BK=32, 256 threads, 4x4 micro-tile per thread.
// LDS tiles stored k-major with XOR swizzle: element (k, m) lives at
// k*64 + ((m>>2 ^ (k&15))<<2) + (m&3)  -> fragment reads are aligned
// ds_read_b128 hitting 2 lanes/bank (free); staging writes ~4-way worst case
// but are only 16 scalar writes per thread per k-tile.
// DUAL: blockIdx.z selects weight/bias/output set (fuses Q+V projections).
// ---------------------------------------------------------------------------
template<int K, bool RELU, bool DUAL>
__global__ __launch_bounds__(256) void gemm_bias(
    const float* __restrict__ X,
    const float* __restrict__ W0, const float* __restrict__ b0, float* __restrict__ C0,
    const float* __restrict__ W1, const float* __restrict__ b1, float* __restrict__ C1,
    int O) {
  constexpr int BK = 32;
  const float* W = (DUAL && blockIdx.z == 1) ? W1 : W0;
  const float* bp = (DUAL && blockIdx.z == 1) ? b1 : b0;
  float* C = (DUAL && blockIdx.z == 1) ? C1 : C0;
  __shared__ float Xs[BK * 64];
  __shared__ float Ws[BK * 64];
  const int t = threadIdx.x;
  const int tn = t & 15, tm = t >> 4;   // tn fast -> contiguous 256B stores
  const int r0 = blockIdx.x * 64, o0 = blockIdx.y * 64;
  float acc[4][4] = {};
  for (int k0 = 0; k0 < K; k0 += BK) {
#pragma unroll
    for (int p = 0; p < 2; ++p) {
      int i4 = t + p * 256;             // 512 float4s per tile
      int m = i4 >> 3;                  // row within tile (0..63)
      int k4 = (i4 & 7) << 2;           // k offset (0,4,..,28)
      int m4 = m >> 2, ml = m & 3;
      float4 vx = *(const float4*)&X[(r0 + m) * K + k0 + k4];
      float4 vw = *(const float4*)&W[(o0 + m) * K + k0 + k4];
      Xs[(k4 + 0) * 64 + ((m4 ^ ((k4 + 0) & 15)) << 2) + ml] = vx.x;
      Xs[(k4 + 1) * 64 + ((m4 ^ ((k4 + 1) & 15)) << 2) + ml] = vx.y;
      Xs[(k4 + 2) * 64 + ((m4 ^ ((k4 + 2) & 15)) << 2) + ml] = vx.z;
      Xs[(k4 + 3) * 64 + ((m4 ^ ((k4 + 3) & 15)) << 2) + ml] = vx.w;
      Ws[(k4 + 0) * 64 + ((m4 ^ ((k4 + 0) & 15)) << 2) + ml] = vw.x;
      Ws[(k4 + 1) * 64 + ((m4 ^ ((k4 + 1) & 15)) << 2) + ml] = vw.y;
      Ws[(k4 + 2) * 64 + ((m4 ^ ((k4 + 2) & 15)) << 2) + ml] = vw.z;
      Ws[(k4 + 3) * 64 + ((m4 ^ ((k4 + 3) & 15)) << 2) + ml] = vw.w;
    }
    __syncthreads();
#pragma unroll
    for (int k = 0; k < BK; ++k) {
      float4 a = *(const float4*)&Xs[k * 64 + ((tm ^ (k & 15)) << 2)];
      float4 b = *(const float4*)&Ws[k * 64 + ((tn ^ (k & 15)) << 2)];
      acc[0][0] += a.x * b.x; acc[0][1] += a.x * b.y; acc[0][2] += a.x * b.z; acc[0][3] += a.x * b.w;
      acc[1][0] += a.y * b.x; acc[1][1] += a.y * b.y; acc[1][2] += a.y * b.z; acc[1][3] += a.y * b.w;
      acc[2][0] += a.z * b.x; acc[2][1] += a.z * b.y; acc[2][2] += a.z * b.z; acc[2][3] += a.z * b.w;
      acc[3][0] += a.w * b.x; acc[3][1] += a.w * b.y; acc[3][2] += a.w * b.z; acc[3][3] += a.w * b.w;
    }
    __syncthreads();
  }
  float4 bv = *(const float4*)&bp[o0 + tn * 4];
#pragma unroll
  for (int i = 0; i < 4; ++i) {
    float4 o;
    o.x = acc[i][0] + bv.x; o.y = acc[i][1] + bv.y;
    o.z = acc[i][2] + bv.z; o.w = acc[i][3] + bv.w;
    if (RELU) {
      o.x = fmaxf(o.x, 0.f); o.y = fmaxf(o.y, 0.f);
      o.z = fmaxf(o.z, 0.f); o.w = fmaxf(o.w, 0.f);
    }
    *(float4*)&C[(r0 + tm * 4 + i) * O + o0 + tn * 4] = o;
  }
}

// ---------------------------------------------------------------------------
// Fused tiny K-projections (O=H=4): NK = node_in @ nkW^T + nkb, EK likewise.
// One thread per output element. 80 blocks.
// ---------------------------------------------------------------------------
__global__ void small_proj(const float* __restrict__ Xn, const float* __restrict__ Wn,
                           const float* __restrict__ bn, float* __restrict__ Cn,
                           const float* __restrict__ Xe, const float* __restrict__ We,
                           const float* __restrict__ be, float* __restrict__ Ce) {
  int idx = blockIdx.x * 256 + threadIdx.x;
  if (idx < N_ * H_) {
    int r = idx >> 2, o = idx & 3;
    const float4* x4 = (const float4*)(Xn + r * FN_);
    const float4* w4 = (const float4*)(Wn + o * FN_);
    float acc = bn[o];
    for (int k = 0; k < FN_ / 4; ++k) {
      float4 x = x4[k], w = w4[k];
      acc += x.x * w.x + x.y * w.y + x.z * w.z + x.w * w.w;
    }
    Cn[idx] = acc;   // flat [N,H] row-major == reshape(H,N,1) flat view
  } else {
    int j = idx - N_ * H_;
    int r = j >> 2, o = j & 3;
    const float4* x4 = (const float4*)(Xe + r * FE_);
    const float4* w4 = (const float4*)(We + o * FE_);
    float acc = be[o];
    for (int k = 0; k < FE_ / 4; ++k) {
      float4 x = x4[k], w = w4[k];
      acc += x.x * w.x + x.y * w.y + x.z * w.z + x.w * w.w;
    }
    Ce[j] = acc;
  }
}

// ---------------------------------------------------------------------------
// Fused self-attention softmax. Blocks 0..3: node heads; 4..7: edge heads.
// t[f] = sum_i q[i,f]*k[i]; s[i] = q[i,:].t; sa = softmax_i(s).
// ---------------------------------------------------------------------------
__global__ __launch_bounds__(1024) void attn(const float* __restrict__ NQ,
                                             const float* __restrict__ NK,
                                             float* __restrict__ nsa,
                                             const float* __restrict__ EQ,
                                             const float* __restrict__ EK,
                                             float* __restrict__ esa) {
  __shared__ float red[1024];
  __shared__ float t[FN_];
  const int tid = threadIdx.x;
  if (blockIdx.x < H_) {
    const int h = blockIdx.x;
    const float* q = NQ + h * (N_ * FN_);
    const float* kk = NK + h * N_;
    {
      int f = tid & (FN_ - 1), c = tid >> 7;  // 8 chunks x 128 rows
      float p = 0.f;
      for (int i = c * 128; i < c * 128 + 128; ++i) p += q[i * FN_ + f] * kk[i];
      red[tid] = p;
    }
    __syncthreads();
    if (tid < FN_) {
      float s = 0.f;
      for (int c = 0; c < 8; ++c) s += red[c * FN_ + tid];
      t[tid] = s;
    }
    __syncthreads();
    float s = 0.f;
    {
      const float4* qr = (const float4*)(q + tid * FN_);
      for (int f4 = 0; f4 < FN_ / 4; ++f4) {
        float4 qq = qr[f4];
        s += qq.x * t[4 * f4] + qq.y * t[4 * f4 + 1] + qq.z * t[4 * f4 + 2] + qq.w * t[4 * f4 + 3];
      }
    }
    red[tid] = s;
    __syncthreads();
    for (int off = 512; off > 0; off >>= 1) {
      if (tid < off) red[tid] = fmaxf(red[tid], red[tid + off]);
      __syncthreads();
    }
    float m = red[0];
    __syncthreads();
    float e = expf(s - m);
    red[tid] = e;
    __syncthreads();
    for (int off = 512; off > 0; off >>= 1) {
      if (tid < off) red[tid] += red[tid + off];
      __syncthreads();
    }
    nsa[h * N_ + tid] = e / red[0];
  } else {
    const int h = blockIdx.x - H_;
    const float* q = EQ + h * (E_ * FE_);
    const float* kk = EK + h * E_;
    {
      int f = tid & (FE_ - 1), c = tid >> 6;  // 16 chunks x 256 rows
      float p = 0.f;
      for (int j = c * 256; j < c * 256 + 256; ++j) p += q[j * FE_ + f] * kk[j];
      red[tid] = p;
    }
    __syncthreads();
    if (tid < FE_) {
      float s = 0.f;
      for (int c = 0; c < 16; ++c) s += red[c * FE_ + tid];
      t[tid] = s;
    }
    __syncthreads();
    float s[4], lm = -INFINITY;
#pragma unroll
    for (int u = 0; u < 4; ++u) {
      const float4* qr = (const float4*)(q + (tid * 4 + u) * FE_);
      float acc = 0.f;
      for (int f4 = 0; f4 < FE_ / 4; ++f4) {
        float4 qq = qr[f4];
        acc += qq.x * t[4 * f4] + qq.y * t[4 * f4 + 1] + qq.z * t[4 * f4 + 2] + qq.w * t[4 * f4 + 3];
      }
      s[u] = acc;
      lm = fmaxf(lm, acc);
    }
    red[tid] = lm;
    __syncthreads();
    for (int off = 512; off > 0; off >>= 1) {
      if (tid < off) red[tid] = fmaxf(red[tid], red[tid + off]);
      __syncthreads();
    }
    float m = red[0];
    __syncthreads();
    float ev[4], le = 0.f;
#pragma unroll
    for (int u = 0; u < 4; ++u) { ev[u] = expf(s[u] - m); le += ev[u]; }
    red[tid] = le;
    __syncthreads();
    for (int off = 512; off > 0; off >>= 1) {
      if (tid < off) red[tid] += red[tid + off];
      __syncthreads();
    }
    float inv = 1.f / red[0];
#pragma unroll
    for (int u = 0; u < 4; ++u) esa[h * E_ + tid * 4 + u] = ev[u] * inv;
  }
}

// ---------------------------------------------------------------------------
// Fused duplicate-winner pass (numpy last-index-wins == max index).
// idx < E: node dense map atomicMax. Else: hash insert for line-graph pairs.
// ---------------------------------------------------------------------------
__global__ void winners(const int* __restrict__ src, const int* __restrict__ dst,
                        int* __restrict__ Wn,
                        const int* __restrict__ lgs, const int* __restrict__ lgd,
                        int* __restrict__ hkey, int* __restrict__ hval) {
  int idx = blockIdx.x * 256 + threadIdx.x;
  if (idx < E_) {
    atomicMax(&Wn[src[idx] * N_ + dst[idx]], idx);
  } else {
    int l = idx - E_;
    int key = lgs[l] * E_ + lgd[l];
    unsigned slot = (((unsigned)key * 2654435761u) >> 16) & (HT_ - 1);
    while (true) {
      int prev = atomicCAS(&hkey[slot], -1, key);
      if (prev == -1 || prev == key) break;
      slot = (slot + 1) & (HT_ - 1);
    }
    atomicMax(&hval[slot], l);
  }
}

// ---------------------------------------------------------------------------
// Fused sparse (proj * A) @ V scatter-accumulate.
// blocks [0, 2048):  node side, thread=(e,f), loops h, winner check via Wn.
// blocks [2048, 6144): edge side, thread=(l,f), hash-probe winner check.
// ---------------------------------------------------------------------------
__global__ void scatter(const int* __restrict__ src, const int* __restrict__ dst,
                        const int* __restrict__ Wn, const float* __restrict__ esa,
                        const float* __restrict__ NV, float* __restrict__ nagg,
                        const int* __restrict__ lgs, const int* __restrict__ lgd,
                        const int* __restrict__ hkey, const int* __restrict__ hval,
                        const float* __restrict__ nsa, const float* __restrict__ EV,
                        float* __restrict__ eagg) {
  const int NODE_BLOCKS = (E_ * FN_) / 256;
  if (blockIdx.x < NODE_BLOCKS) {
    int idx = blockIdx.x * 256 + threadIdx.x;
    int e = idx >> 7, f = idx & (FN_ - 1);
    int s = src[e], d = dst[e];
    if (Wn[s * N_ + d] != e) return;
#pragma unroll
    for (int h = 0; h < H_; ++h)
      atomicAdd(&nagg[h * (N_ * FN_) + s * FN_ + f],
                esa[h * E_ + e] * NV[h * (N_ * FN_) + d * FN_ + f]);
  } else {
    int idx = (blockIdx.x - NODE_BLOCKS) * 256 + threadIdx.x;
    int l = idx >> 6, f = idx & (FE_ - 1);
    int j = lgs[l], c = lgd[l];
    int key = j * E_ + c;
    unsigned slot = (((unsigned)key * 2654435761u) >> 16) & (HT_ - 1);
    while (hkey[slot] != key) slot = (slot + 1) & (HT_ - 1);
    if (hval[slot] != l) return;
    int cn = dst[j];
#pragma unroll
    for (int h = 0; h < H_; ++h)
      atomicAdd(&eagg[h * (E_ * FE_) + j * FE_ + f],
                nsa[h * N_ + cn] * EV[h * (E_ * FE_) + c * FE_ + f]);
  }
}

// ---------------------------------------------------------------------------
extern "C" void kernel_launch(void* const* d_in, const int* in_sizes, int n_in,
                              void* d_out, int out_size, void* d_ws, size_t ws_size,
                              hipStream_t stream) {
  const float* node_inputs = (const float*)d_in[0];
  const float* edge_inputs = (const float*)d_in[1];
  const int*   src    = (const int*)d_in[2];
  const int*   dst    = (const int*)d_in[3];
  const int*   lg_src = (const int*)d_in[4];
  const int*   lg_dst = (const int*)d_in[5];
  const float* nqW = (const float*)d_in[6];
  const float* nqb = (const float*)d_in[7];
  const float* nkW = (const float*)d_in[8];
  const float* nkb = (const float*)d_in[9];
  const float* nvW = (const float*)d_in[10];
  const float* nvb = (const float*)d_in[11];
  const float* eqW = (const float*)d_in[12];
  const float* eqb = (const float*)d_in[13];
  const float* ekW = (const float*)d_in[14];
  const float* ekb = (const float*)d_in[15];
  const float* evW = (const float*)d_in[16];
  const float* evb = (const float*)d_in[17];
  const float* ncW = (const float*)d_in[18];
  const float* ncb = (const float*)d_in[19];
  const float* ecW = (const float*)d_in[20];
  const float* ecb = (const float*)d_in[21];
  float* out = (float*)d_out;

  // workspace carve-up (floats); nagg/eagg contiguous, Wn/hkey/hval contiguous
  float* f  = (float*)d_ws;
  float* NQ   = f; f += N_ * H_ * FN_;
  float* NV   = f; f += N_ * H_ * FN_;
  float* EQ   = f; f += E_ * H_ * FE_;
  float* EV   = f; f += E_ * H_ * FE_;
  float* NK   = f; f += N_ * H_;
  float* EK   = f; f += E_ * H_;
  float* nsa  = f; f += H_ * N_;
  float* esa  = f; f += H_ * E_;
  float* nagg = f; f += H_ * N_ * FN_;
  float* eagg = f; f += H_ * E_ * FE_;
  int*   Wn   = (int*)f; f += N_ * N_;
  int*   hkey = (int*)f; f += HT_;
  int*   hval = (int*)f; f += HT_;

  hipMemsetAsync(nagg, 0, (size_t)(H_ * N_ * FN_ + H_ * E_ * FE_) * 4, stream);
  hipMemsetAsync(Wn, 0xFF, (size_t)(N_ * N_ + 2 * HT_) * 4, stream);

  // projections (DUAL fuses Q+V via blockIdx.z)
  gemm_bias<128, false, true><<<dim3(16, 8, 2), 256, 0, stream>>>(
      node_inputs, nqW, nqb, NQ, nvW, nvb, NV, H_ * FN_);
  gemm_bias<64, false, true><<<dim3(64, 4, 2), 256, 0, stream>>>(
      edge_inputs, eqW, eqb, EQ, evW, evb, EV, H_ * FE_);
  small_proj<<<80, 256, 0, stream>>>(node_inputs, nkW, nkb, NK,
                                     edge_inputs, ekW, ekb, EK);

  attn<<<2 * H_, 1024, 0, stream>>>(NQ, NK, nsa, EQ, EK, esa);
  winners<<<(E_ + LE_) / 256, 256, 0, stream>>>(src, dst, Wn, lg_src, lg_dst, hkey, hval);
  scatter<<<(E_ * FN_ + LE_ * FE_) / 256, 256, 0, stream>>>(
      src, dst, Wn, esa, NV, nagg, lg_src, lg_dst, hkey, hval, nsa, EV, eagg);

  // output linears + ReLU into d_out
  gemm_bias<128, true, false><<<dim3(64, 2, 1), 256, 0, stream>>>(
      nagg, ncW, ncb, out, nullptr, nullptr, nullptr, 128);
  gemm_bias<64, true, false><<<dim3(256, 1, 1), 256, 0, stream>>>(
      eagg, ecW, ecb, out + (size_t)H_ * N_ * 128, nullptr, nullptr, nullptr, 64);
}

// Round 3
// 196.532 us; speedup vs baseline: 3.9624x; 1.3614x over previous
//
#include <hip/hip_runtime.h>

#define H_ 4
#define N_ 1024
#define E_ 4096
#define LE_ 16384
#define FN_ 128
#define FE_ 64
#define HT_ 65536   // hash table slots (4x oversized vs LE entries)

// ---------------------------------------------------------------------------
// Register-tiled GEMM: C = [relu](X @ W^T + b). X:[R,K], W:[O,K], C:[R,O].
// BM=BN=64, BK=32, 256 threads, 4x4 micro-tile per thread, XOR-swizzled LDS.
// ---------------------------------------------------------------------------
template<int K, bool RELU>
__global__ __launch_bounds__(256) void gemm_bias(
    const float* __restrict__ X, const float* __restrict__ W,
    const float* __restrict__ b, float* __restrict__ C, int O) {
  constexpr int BK = 32;
  __shared__ float Xs[BK * 64];
  __shared__ float Ws[BK * 64];
  const int t = threadIdx.x;
  const int tn = t & 15, tm = t >> 4;
  const int r0 = blockIdx.x * 64, o0 = blockIdx.y * 64;
  float acc[4][4] = {};
  for (int k0 = 0; k0 < K; k0 += BK) {
#pragma unroll
    for (int p = 0; p < 2; ++p) {
      int i4 = t + p * 256;
      int m = i4 >> 3;
      int k4 = (i4 & 7) << 2;
      int m4 = m >> 2, ml = m & 3;
      float4 vx = *(const float4*)&X[(r0 + m) * K + k0 + k4];
      float4 vw = *(const float4*)&W[(o0 + m) * K + k0 + k4];
      Xs[(k4 + 0) * 64 + ((m4 ^ ((k4 + 0) & 15)) << 2) + ml] = vx.x;
      Xs[(k4 + 1) * 64 + ((m4 ^ ((k4 + 1) & 15)) << 2) + ml] = vx.y;
      Xs[(k4 + 2) * 64 + ((m4 ^ ((k4 + 2) & 15)) << 2) + ml] = vx.z;
      Xs[(k4 + 3) * 64 + ((m4 ^ ((k4 + 3) & 15)) << 2) + ml] = vx.w;
      Ws[(k4 + 0) * 64 + ((m4 ^ ((k4 + 0) & 15)) << 2) + ml] = vw.x;
      Ws[(k4 + 1) * 64 + ((m4 ^ ((k4 + 1) & 15)) << 2) + ml] = vw.y;
      Ws[(k4 + 2) * 64 + ((m4 ^ ((k4 + 2) & 15)) << 2) + ml] = vw.z;
      Ws[(k4 + 3) * 64 + ((m4 ^ ((k4 + 3) & 15)) << 2) + ml] = vw.w;
    }
    __syncthreads();
#pragma unroll
    for (int k = 0; k < BK; ++k) {
      float4 a = *(const float4*)&Xs[k * 64 + ((tm ^ (k & 15)) << 2)];
      float4 b4 = *(const float4*)&Ws[k * 64 + ((tn ^ (k & 15)) << 2)];
      acc[0][0] += a.x * b4.x; acc[0][1] += a.x * b4.y; acc[0][2] += a.x * b4.z; acc[0][3] += a.x * b4.w;
      acc[1][0] += a.y * b4.x; acc[1][1] += a.y * b4.y; acc[1][2] += a.y * b4.z; acc[1][3] += a.y * b4.w;
      acc[2][0] += a.z * b4.x; acc[2][1] += a.z * b4.y; acc[2][2] += a.z * b4.z; acc[2][3] += a.z * b4.w;
      acc[3][0] += a.w * b4.x; acc[3][1] += a.w * b4.y; acc[3][2] += a.w * b4.z; acc[3][3] += a.w * b4.w;
    }
    __syncthreads();
  }
  float4 bv = *(const float4*)&b[o0 + tn * 4];
#pragma unroll
  for (int i = 0; i < 4; ++i) {
    float4 o;
    o.x = acc[i][0] + bv.x; o.y = acc[i][1] + bv.y;
    o.z = acc[i][2] + bv.z; o.w = acc[i][3] + bv.w;
    if (RELU) {
      o.x = fmaxf(o.x, 0.f); o.y = fmaxf(o.y, 0.f);
      o.z = fmaxf(o.z, 0.f); o.w = fmaxf(o.w, 0.f);
    }
    *(float4*)&C[(r0 + tm * 4 + i) * O + o0 + tn * 4] = o;
  }
}

// ---------------------------------------------------------------------------
// Tiny K-projections (O=H=4), stored in lin layout [rows, 4] flat.
// ---------------------------------------------------------------------------
__global__ void small_proj(const float* __restrict__ Xn, const float* __restrict__ Wn,
                           const float* __restrict__ bn, float* __restrict__ Cn,
                           const float* __restrict__ Xe, const float* __restrict__ We,
                           const float* __restrict__ be, float* __restrict__ Ce) {
  int idx = blockIdx.x * 256 + threadIdx.x;
  if (idx < N_ * H_) {
    int r = idx >> 2, o = idx & 3;
    const float4* x4 = (const float4*)(Xn + r * FN_);
    const float4* w4 = (const float4*)(Wn + o * FN_);
    float acc = bn[o];
    for (int k = 0; k < FN_ / 4; ++k) {
      float4 x = x4[k], w = w4[k];
      acc += x.x * w.x + x.y * w.y + x.z * w.z + x.w * w.w;
    }
    Cn[idx] = acc;
  } else {
    int j = idx - N_ * H_;
    int r = j >> 2, o = j & 3;
    const float4* x4 = (const float4*)(Xe + r * FE_);
    const float4* w4 = (const float4*)(We + o * FE_);
    float acc = be[o];
    for (int k = 0; k < FE_ / 4; ++k) {
      float4 x = x4[k], w = w4[k];
      acc += x.x * w.x + x.y * w.y + x.z * w.z + x.w * w.w;
    }
    Ce[j] = acc;
  }
}

// ---------------------------------------------------------------------------
// Factored self-attention. softmax(Q (Q^T k)) with Q = X W^T + b substituted:
// head h, position i=4j+c maps to lin row r = rowbase + j, weight slice c.
//   y_c[g]   = sum_j X[r,g] * Klin[r,c];  sigma_c = sum_j Klin[r,c]
//   t[f]     = sum_c ( Wq_c[f,:].y_c + sigma_c * b_c[f] )
//   z_c[g]   = sum_f Wq[c*F+f, g] * t[f];  d_c = sum_f b_c[f] t[f]
//   s[4j+c]  = X[r,:].z_c + d_c  -> softmax over i
// Blocks 0..3 = node heads (F=128, 256 rows); 4..7 = edge heads (F=64, 1024).
// ---------------------------------------------------------------------------
__global__ __launch_bounds__(1024) void attn_fact(
    const float* __restrict__ Xn, const float* __restrict__ NK,
    const float* __restrict__ nqW, const float* __restrict__ nqb,
    float* __restrict__ nsa,
    const float* __restrict__ Xe, const float* __restrict__ EK,
    const float* __restrict__ eqW, const float* __restrict__ eqb,
    float* __restrict__ esa) {
  __shared__ float4 accs[1024];   // 16 KB reduce scratch
  __shared__ float red[1024];
  __shared__ float ys[512];       // y[g*4+c]
  __shared__ float ts[128];
  __shared__ float zs[4 * 132];   // z[c*STRIDE+g], stride%32=4 -> no conflicts
  __shared__ float ds[4], sig[4];
  const int tid = threadIdx.x;

  if (blockIdx.x < 4) {
    // ---------------- node head ----------------
    const int h = blockIdx.x;
    const int r0 = h * 256;
    // y: g = tid&127, q = tid>>7 (8 chunks x 32 rows)
    {
      int g = tid & 127, q = tid >> 7;
      float a0 = 0, a1 = 0, a2 = 0, a3 = 0;
      for (int jj = 0; jj < 32; ++jj) {
        int r = r0 + q * 32 + jj;
        float x = Xn[r * FN_ + g];
        float4 k = ((const float4*)NK)[r];
        a0 += x * k.x; a1 += x * k.y; a2 += x * k.z; a3 += x * k.w;
      }
      accs[tid] = make_float4(a0, a1, a2, a3);
    }
    __syncthreads();
    for (int off = 512; off >= 128; off >>= 1) {
      if (tid < off) {
        float4 a = accs[tid], b = accs[tid + off];
        accs[tid] = make_float4(a.x + b.x, a.y + b.y, a.z + b.z, a.w + b.w);
      }
      __syncthreads();
    }
    if (tid < 128) {
      float4 a = accs[tid];
      ys[tid * 4 + 0] = a.x; ys[tid * 4 + 1] = a.y;
      ys[tid * 4 + 2] = a.z; ys[tid * 4 + 3] = a.w;
    }
    // sigma (32 threads: c = t&3, part = t>>2, 8 parts x 32 rows)
    if (tid >= 128 && tid < 160) {
      int t2 = tid - 128, c = t2 & 3, part = t2 >> 2;
      float s = 0.f;
      for (int j = 0; j < 32; ++j) s += NK[(r0 + part * 32 + j) * 4 + c];
      red[t2] = s;
    }
    __syncthreads();
    if (tid < 4) {
      float s = 0.f;
      for (int p = 0; p < 8; ++p) s += red[p * 4 + tid];
      sig[tid] = s;
    }
    __syncthreads();
    // t: threads 0..511, row = tid = c*128+f of nqW
    if (tid < 512) {
      const float4* w4 = (const float4*)(nqW + tid * FN_);
      int c = tid >> 7;
      float s = 0.f;
      for (int g4 = 0; g4 < 32; ++g4) {
        float4 w = w4[g4];
        s += w.x * ys[(g4 * 4 + 0) * 4 + c] + w.y * ys[(g4 * 4 + 1) * 4 + c]
           + w.z * ys[(g4 * 4 + 2) * 4 + c] + w.w * ys[(g4 * 4 + 3) * 4 + c];
      }
      red[tid] = s;
    }
    __syncthreads();
    if (tid < 128) {
      float s = red[tid] + red[128 + tid] + red[256 + tid] + red[384 + tid];
      float bb = 0.f;
      for (int c = 0; c < 4; ++c) bb += nqb[c * 128 + tid] * sig[c];
      ts[tid] = s + bb;
    }
    __syncthreads();
    // z: threads 0..511 (c = tid>>7, g = tid&127); d: threads 512..515
    if (tid < 512) {
      int c = tid >> 7, g = tid & 127;
      float s = 0.f;
      for (int f = 0; f < 128; ++f) s += nqW[(c * 128 + f) * 128 + g] * ts[f];
      zs[c * 132 + g] = s;
    }
    if (tid >= 512 && tid < 516) {
      int c = tid - 512;
      float s = 0.f;
      for (int f = 0; f < 128; ++f) s += nqb[c * 128 + f] * ts[f];
      ds[c] = s;
    }
    __syncthreads();
    // scores + softmax: thread = position i (i = 4j+c)
    float sc;
    {
      int c = tid & 3, j = tid >> 2;
      const float4* x4 = (const float4*)(Xn + (r0 + j) * FN_);
      const float* z = zs + c * 132;
      float s = ds[c];
      for (int g4 = 0; g4 < 32; ++g4) {
        float4 x = x4[g4];
        s += x.x * z[g4 * 4] + x.y * z[g4 * 4 + 1] + x.z * z[g4 * 4 + 2] + x.w * z[g4 * 4 + 3];
      }
      sc = s;
    }
    red[tid] = sc;
    __syncthreads();
    for (int off = 512; off > 0; off >>= 1) {
      if (tid < off) red[tid] = fmaxf(red[tid], red[tid + off]);
      __syncthreads();
    }
    float m = red[0];
    __syncthreads();
    float e = expf(sc - m);
    red[tid] = e;
    __syncthreads();
    for (int off = 512; off > 0; off >>= 1) {
      if (tid < off) red[tid] += red[tid + off];
      __syncthreads();
    }
    nsa[h * N_ + tid] = e / red[0];
  } else {
    // ---------------- edge head ----------------
    const int h = blockIdx.x - 4;
    const int r0 = h * 1024;
    // y: g = tid&63, q = tid>>6 (16 chunks x 64 rows)
    {
      int g = tid & 63, q = tid >> 6;
      float a0 = 0, a1 = 0, a2 = 0, a3 = 0;
      for (int jj = 0; jj < 64; ++jj) {
        int r = r0 + q * 64 + jj;
        float x = Xe[r * FE_ + g];
        float4 k = ((const float4*)EK)[r];
        a0 += x * k.x; a1 += x * k.y; a2 += x * k.z; a3 += x * k.w;
      }
      accs[tid] = make_float4(a0, a1, a2, a3);
    }
    __syncthreads();
    for (int off = 512; off >= 64; off >>= 1) {
      if (tid < off) {
        float4 a = accs[tid], b = accs[tid + off];
        accs[tid] = make_float4(a.x + b.x, a.y + b.y, a.z + b.z, a.w + b.w);
      }
      __syncthreads();
    }
    if (tid < 64) {
      float4 a = accs[tid];
      ys[tid * 4 + 0] = a.x; ys[tid * 4 + 1] = a.y;
      ys[tid * 4 + 2] = a.z; ys[tid * 4 + 3] = a.w;
    }
    // sigma (32 threads: 8 parts x 128 rows)
    if (tid >= 128 && tid < 160) {
      int t2 = tid - 128, c = t2 & 3, part = t2 >> 2;
      float s = 0.f;
      for (int j = 0; j < 128; ++j) s += EK[(r0 + part * 128 + j) * 4 + c];
      red[t2] = s;
    }
    __syncthreads();
    if (tid < 4) {
      float s = 0.f;
      for (int p = 0; p < 8; ++p) s += red[p * 4 + tid];
      sig[tid] = s;
    }
    __syncthreads();
    // t: threads 0..255, row = tid = c*64+f of eqW
    if (tid < 256) {
      const float4* w4 = (const float4*)(eqW + tid * FE_);
      int c = tid >> 6;
      float s = 0.f;
      for (int g4 = 0; g4 < 16; ++g4) {
        float4 w = w4[g4];
        s += w.x * ys[(g4 * 4 + 0) * 4 + c] + w.y * ys[(g4 * 4 + 1) * 4 + c]
           + w.z * ys[(g4 * 4 + 2) * 4 + c] + w.w * ys[(g4 * 4 + 3) * 4 + c];
      }
      red[tid] = s;
    }
    __syncthreads();
    if (tid < 64) {
      float s = red[tid] + red[64 + tid] + red[128 + tid] + red[192 + tid];
      float bb = 0.f;
      for (int c = 0; c < 4; ++c) bb += eqb[c * 64 + tid] * sig[c];
      ts[tid] = s + bb;
    }
    __syncthreads();
    // z: threads 0..255 (c = tid>>6, g = tid&63); d: threads 256..259
    if (tid < 256) {
      int c = tid >> 6, g = tid & 63;
      float s = 0.f;
      for (int f = 0; f < 64; ++f) s += eqW[(c * 64 + f) * 64 + g] * ts[f];
      zs[c * 132 + g] = s;
    }
    if (tid >= 256 && tid < 260) {
      int c = tid - 256;
      float s = 0.f;
      for (int f = 0; f < 64; ++f) s += eqb[c * 64 + f] * ts[f];
      ds[c] = s;
    }
    __syncthreads();
    // scores + softmax: thread j handles i = 4j..4j+3 (one Xe row)
    float s4[4];
    {
      const float4* x4 = (const float4*)(Xe + (r0 + tid) * FE_);
      s4[0] = ds[0]; s4[1] = ds[1]; s4[2] = ds[2]; s4[3] = ds[3];
      for (int g4 = 0; g4 < 16; ++g4) {
        float4 x = x4[g4];
#pragma unroll
        for (int c = 0; c < 4; ++c) {
          const float* z = zs + c * 132 + g4 * 4;
          s4[c] += x.x * z[0] + x.y * z[1] + x.z * z[2] + x.w * z[3];
        }
      }
    }
    float lm = fmaxf(fmaxf(s4[0], s4[1]), fmaxf(s4[2], s4[3]));
    red[tid] = lm;
    __syncthreads();
    for (int off = 512; off > 0; off >>= 1) {
      if (tid < off) red[tid] = fmaxf(red[tid], red[tid + off]);
      __syncthreads();
    }
    float m = red[0];
    __syncthreads();
    float e0 = expf(s4[0] - m), e1 = expf(s4[1] - m);
    float e2 = expf(s4[2] - m), e3 = expf(s4[3] - m);
    red[tid] = e0 + e1 + e2 + e3;
    __syncthreads();
    for (int off = 512; off > 0; off >>= 1) {
      if (tid < off) red[tid] += red[tid + off];
      __syncthreads();
    }
    float inv = 1.f / red[0];
    float4* o4 = (float4*)(esa + h * E_ + tid * 4);
    *o4 = make_float4(e0 * inv, e1 * inv, e2 * inv, e3 * inv);
  }
}

// ---------------------------------------------------------------------------
// Duplicate winners (numpy last-index-wins == max index).
// ---------------------------------------------------------------------------
__global__ void winners(const int* __restrict__ src, const int* __restrict__ dst,
                        int* __restrict__ Wn,
                        const int* __restrict__ lgs, const int* __restrict__ lgd,
                        int* __restrict__ hkey, int* __restrict__ hval) {
  int idx = blockIdx.x * 256 + threadIdx.x;
  if (idx < E_) {
    atomicMax(&Wn[src[idx] * N_ + dst[idx]], idx);
  } else {
    int l = idx - E_;
    int key = lgs[l] * E_ + lgd[l];
    unsigned slot = (((unsigned)key * 2654435761u) >> 16) & (HT_ - 1);
    while (true) {
      int prev = atomicCAS(&hkey[slot], -1, key);
      if (prev == -1 || prev == key) break;
      slot = (slot + 1) & (HT_ - 1);
    }
    atomicMax(&hval[slot], l);
  }
}

// ---------------------------------------------------------------------------
// Sparse (proj * A) @ V scatter-accumulate.
// ---------------------------------------------------------------------------
__global__ void scatter(const int* __restrict__ src, const int* __restrict__ dst,
                        const int* __restrict__ Wn, const float* __restrict__ esa,
                        const float* __restrict__ NV, float* __restrict__ nagg,
                        const int* __restrict__ lgs, const int* __restrict__ lgd,
                        const int* __restrict__ hkey, const int* __restrict__ hval,
                        const float* __restrict__ nsa, const float* __restrict__ EV,
                        float* __restrict__ eagg) {
  const int NODE_BLOCKS = (E_ * FN_) / 256;
  if (blockIdx.x < NODE_BLOCKS) {
    int idx = blockIdx.x * 256 + threadIdx.x;
    int e = idx >> 7, f = idx & (FN_ - 1);
    int s = src[e], d = dst[e];
    if (Wn[s * N_ + d] != e) return;
#pragma unroll
    for (int h = 0; h < H_; ++h)
      atomicAdd(&nagg[h * (N_ * FN_) + s * FN_ + f],
                esa[h * E_ + e] * NV[h * (N_ * FN_) + d * FN_ + f]);
  } else {
    int idx = (blockIdx.x - NODE_BLOCKS) * 256 + threadIdx.x;
    int l = idx >> 6, f = idx & (FE_ - 1);
    int j = lgs[l], c = lgd[l];
    int key = j * E_ + c;
    unsigned slot = (((unsigned)key * 2654435761u) >> 16) & (HT_ - 1);
    while (hkey[slot] != key) slot = (slot + 1) & (HT_ - 1);
    if (hval[slot] != l) return;
    int cn = dst[j];
#pragma unroll
    for (int h = 0; h < H_; ++h)
      atomicAdd(&eagg[h * (E_ * FE_) + j * FE_ + f],
                nsa[h * N_ + cn] * EV[h * (E_ * FE_) + c * FE_ + f]);
  }
}

// ---------------------------------------------------------------------------
extern "C" void kernel_launch(void* const* d_in, const int* in_sizes, int n_in,
                              void* d_out, int out_size, void* d_ws, size_t ws_size,
                              hipStream_t stream) {
  const float* node_inputs = (const float*)d_in[0];
  const float* edge_inputs = (const float*)d_in[1];
  const int*   src    = (const int*)d_in[2];
  const int*   dst    = (const int*)d_in[3];
  const int*   lg_src = (const int*)d_in[4];
  const int*   lg_dst = (const int*)d_in[5];
  const float* nqW = (const float*)d_in[6];
  const float* nqb = (const float*)d_in[7];
  const float* nkW = (const float*)d_in[8];
  const float* nkb = (const float*)d_in[9];
  const float* nvW = (const float*)d_in[10];
  const float* nvb = (const float*)d_in[11];
  const float* eqW = (const float*)d_in[12];
  const float* eqb = (const float*)d_in[13];
  const float* ekW = (const float*)d_in[14];
  const float* ekb = (const float*)d_in[15];
  const float* evW = (const float*)d_in[16];
  const float* evb = (const float*)d_in[17];
  const float* ncW = (const float*)d_in[18];
  const float* ncb = (const float*)d_in[19];
  const float* ecW = (const float*)d_in[20];
  const float* ecb = (const float*)d_in[21];
  float* out = (float*)d_out;

  float* f  = (float*)d_ws;
  float* NV   = f; f += N_ * H_ * FN_;
  float* EV   = f; f += E_ * H_ * FE_;
  float* NK   = f; f += N_ * H_;
  float* EK   = f; f += E_ * H_;
  float* nsa  = f; f += H_ * N_;
  float* esa  = f; f += H_ * E_;
  float* nagg = f; f += H_ * N_ * FN_;
  float* eagg = f; f += H_ * E_ * FE_;
  int*   Wn   = (int*)f; f += N_ * N_;
  int*   hkey = (int*)f; f += HT_;
  int*   hval = (int*)f; f += HT_;

  hipMemsetAsync(nagg, 0, (size_t)(H_ * N_ * FN_ + H_ * E_ * FE_) * 4, stream);
  hipMemsetAsync(Wn, 0xFF, (size_t)(N_ * N_ + 2 * HT_) * 4, stream);

  // V projections + tiny K projections
  gemm_bias<128, false><<<dim3(16, 8), 256, 0, stream>>>(node_inputs, nvW, nvb, NV, H_ * FN_);
  gemm_bias<64, false><<<dim3(64, 4), 256, 0, stream>>>(edge_inputs, evW, evb, EV, H_ * FE_);
  small_proj<<<80, 256, 0, stream>>>(node_inputs, nkW, nkb, NK,
                                     edge_inputs, ekW, ekb, EK);

  // factored attention (replaces Q GEMMs + old attn)
  attn_fact<<<8, 1024, 0, stream>>>(node_inputs, NK, nqW, nqb, nsa,
                                    edge_inputs, EK, eqW, eqb, esa);

  winners<<<(E_ + LE_) / 256, 256, 0, stream>>>(src, dst, Wn, lg_src, lg_dst, hkey, hval);
  scatter<<<(E_ * FN_ + LE_ * FE_) / 256, 256, 0, stream>>>(
      src, dst, Wn, esa, NV, nagg, lg_src, lg_dst, hkey, hval, nsa, EV, eagg);

  // output linears + ReLU into d_out
  gemm_bias<128, true><<<dim3(64, 2), 256, 0, stream>>>(nagg, ncW, ncb, out, 128);
  gemm_bias<64, true><<<dim3(256, 1), 256, 0, stream>>>(eagg, ecW, ecb, out + (size_t)H_ * N_ * 128, 64);
}